// Round 10
// baseline (236.603 us; speedup 1.0000x reference)
//
#include <hip/hip_runtime.h>
#include <hip/hip_bf16.h>

#define N 4096
#define D 256
#define MARGIN 0.3f
#define NPANEL 64                       // 4096 / 64
#define NSLOT 65                        // slots per panel, each written exactly once
#define NTILE (NPANEL * (NPANEL + 1) / 2)   // 2080 triangular tiles
#define FLT_BIG 3.402823466e+38f

typedef __attribute__((ext_vector_type(8))) short short8;
typedef __attribute__((ext_vector_type(4))) float f32x4;

__device__ __forceinline__ ushort f2bf(float f) {
    unsigned u = __float_as_uint(f);
    return (ushort)((u + 0x7fffu + ((u >> 16) & 1u)) >> 16);   // RNE
}

// Coherent (agent-scope, L2-bypassing) accessors for the cross-XCD partials.
// Per-access sc0/sc1 — NO cache-wide fences (threadfence = full L2 flush on
// gfx950, measured 195 MB write storms in round 9).
__device__ __forceinline__ void cstore(float* p, float v) {
    __hip_atomic_store(p, v, __ATOMIC_RELAXED, __HIP_MEMORY_SCOPE_AGENT);
}
__device__ __forceinline__ float cload(const float* p) {
    return __hip_atomic_load(p, __ATOMIC_RELAXED, __HIP_MEMORY_SCOPE_AGENT);
}

// Single fused kernel: fp32->bf16 conversion + row norms (per-block,
// redundant but deterministic), 64x64 triangular MFMA distance tile, masked
// row/col max/min partials, ticket-driven panel merges + final loss.
__global__ __launch_bounds__(256, 4) void fused_kernel(
        const float* __restrict__ feat, const int* __restrict__ labels,
        float* __restrict__ pPart, float* __restrict__ nPart,
        float* __restrict__ gacc, unsigned* __restrict__ ticket,
        unsigned* __restrict__ panelCnt, float* __restrict__ out) {
    __shared__ __attribute__((aligned(16))) short sA[64 * 64];   // 8 KB
    __shared__ __attribute__((aligned(16))) short sB[64 * 64];   // 8 KB
    __shared__ float rp[4][32], rn[4][32], cp[4][32], cn[4][32]; // 2 KB
    __shared__ float sXA[64], sXB[64];                           // 512 B
    __shared__ float mpL[4][64], mnL[4][64];                     // 2 KB
    __shared__ int flags[2];

    const int tid  = threadIdx.x;
    const int lane = tid & 63;
    const int wid  = tid >> 6;

    // triangular decode: blockIdx.x -> (bi, bj) with bj >= bi
    int t = blockIdx.x, bi = 0, rem = NPANEL;
    while (t >= rem) { t -= rem; ++bi; --rem; }
    const int bj = bi + t;
    const int rowBase = bi * 64;
    const int colBase = bj * 64;

    // staging geometry: chunk c -> row c>>3, pre-swizzled k-chunk ((c^row)&7)*8
    const int row0 = tid >> 3;            // chunk c0 = tid       (rows 0..31)
    const int row1 = 32 + row0;           // chunk c1 = 256 + tid (rows 32..63)
    const int kc0  = ((tid ^ row0) & 7) * 8;
    const int kc1  = (((256 + tid) ^ row1) & 7) * 8;

    const int wr  = (wid >> 1) * 32;
    const int wc  = (wid & 1) * 32;
    const int l15 = lane & 15;
    const int kq  = (lane >> 4) * 8;
    const int swz = (lane & 7) << 3;      // ushort-index XOR swizzle

    float xA0 = 0.0f, xA1 = 0.0f, xB0 = 0.0f, xB1 = 0.0f;
    f32x4 acc[2][2] = {};

    for (int kt = 0; kt < D; kt += 64) {
        // ---- reg-stage fp32 -> bf16, accumulate squared norms ----
        {
            float4 a0 = *(const float4*)(feat + (size_t)(rowBase + row0) * D + kt + kc0);
            float4 a1 = *(const float4*)(feat + (size_t)(rowBase + row0) * D + kt + kc0 + 4);
            float4 a2 = *(const float4*)(feat + (size_t)(rowBase + row1) * D + kt + kc1);
            float4 a3 = *(const float4*)(feat + (size_t)(rowBase + row1) * D + kt + kc1 + 4);
            float4 b0 = *(const float4*)(feat + (size_t)(colBase + row0) * D + kt + kc0);
            float4 b1 = *(const float4*)(feat + (size_t)(colBase + row0) * D + kt + kc0 + 4);
            float4 b2 = *(const float4*)(feat + (size_t)(colBase + row1) * D + kt + kc1);
            float4 b3 = *(const float4*)(feat + (size_t)(colBase + row1) * D + kt + kc1 + 4);
            xA0 += a0.x*a0.x + a0.y*a0.y + a0.z*a0.z + a0.w*a0.w
                 + a1.x*a1.x + a1.y*a1.y + a1.z*a1.z + a1.w*a1.w;
            xA1 += a2.x*a2.x + a2.y*a2.y + a2.z*a2.z + a2.w*a2.w
                 + a3.x*a3.x + a3.y*a3.y + a3.z*a3.z + a3.w*a3.w;
            xB0 += b0.x*b0.x + b0.y*b0.y + b0.z*b0.z + b0.w*b0.w
                 + b1.x*b1.x + b1.y*b1.y + b1.z*b1.z + b1.w*b1.w;
            xB1 += b2.x*b2.x + b2.y*b2.y + b2.z*b2.z + b2.w*b2.w
                 + b3.x*b3.x + b3.y*b3.y + b3.z*b3.z + b3.w*b3.w;
            short8 sa0 = { (short)f2bf(a0.x), (short)f2bf(a0.y), (short)f2bf(a0.z), (short)f2bf(a0.w),
                           (short)f2bf(a1.x), (short)f2bf(a1.y), (short)f2bf(a1.z), (short)f2bf(a1.w) };
            short8 sa1 = { (short)f2bf(a2.x), (short)f2bf(a2.y), (short)f2bf(a2.z), (short)f2bf(a2.w),
                           (short)f2bf(a3.x), (short)f2bf(a3.y), (short)f2bf(a3.z), (short)f2bf(a3.w) };
            short8 sb0 = { (short)f2bf(b0.x), (short)f2bf(b0.y), (short)f2bf(b0.z), (short)f2bf(b0.w),
                           (short)f2bf(b1.x), (short)f2bf(b1.y), (short)f2bf(b1.z), (short)f2bf(b1.w) };
            short8 sb1 = { (short)f2bf(b2.x), (short)f2bf(b2.y), (short)f2bf(b2.z), (short)f2bf(b2.w),
                           (short)f2bf(b3.x), (short)f2bf(b3.y), (short)f2bf(b3.z), (short)f2bf(b3.w) };
            *(short8*)(sA + tid * 8)         = sa0;
            *(short8*)(sA + (256 + tid) * 8) = sa1;
            *(short8*)(sB + tid * 8)         = sb0;
            *(short8*)(sB + (256 + tid) * 8) = sb1;
        }
        __syncthreads();
        #pragma unroll
        for (int h = 0; h < 2; ++h) {
            short8 af[2], bfv[2];
            #pragma unroll
            for (int m = 0; m < 2; ++m) {
                int idx = ((wr + m * 16 + l15) << 6) + h * 32 + kq;
                af[m] = *(const short8*)(sA + (idx ^ swz));
            }
            #pragma unroll
            for (int n = 0; n < 2; ++n) {
                int idx = ((wc + n * 16 + l15) << 6) + h * 32 + kq;
                bfv[n] = *(const short8*)(sB + (idx ^ swz));
            }
            #pragma unroll
            for (int m = 0; m < 2; ++m)
                #pragma unroll
                for (int n = 0; n < 2; ++n)
                    acc[m][n] = __builtin_amdgcn_mfma_f32_16x16x32_bf16(
                        af[m], bfv[n], acc[m][n], 0, 0, 0);
        }
        __syncthreads();
    }

    // finalize row norms: sum the 8 chunk-threads of each row (lane bits 0..2)
    #pragma unroll
    for (int off = 1; off <= 4; off <<= 1) {
        xA0 += __shfl_xor(xA0, off); xA1 += __shfl_xor(xA1, off);
        xB0 += __shfl_xor(xB0, off); xB1 += __shfl_xor(xB1, off);
    }
    if ((lane & 7) == 0) {
        sXA[row0] = xA0; sXA[row1] = xA1;
        sXB[row0] = xB0; sXB[row1] = xB1;
    }
    __syncthreads();

    // ---- epilogue in d^2 domain ----
    float xr[2][4]; int lrow[2][4];
    #pragma unroll
    for (int m = 0; m < 2; ++m)
        #pragma unroll
        for (int j = 0; j < 4; ++j) {
            int lr = wr + m * 16 + (lane >> 4) * 4 + j;
            xr[m][j] = sXA[lr]; lrow[m][j] = labels[rowBase + lr];
        }
    float xc[2]; int lcol[2];
    #pragma unroll
    for (int n = 0; n < 2; ++n) {
        int lc = wc + n * 16 + l15;
        xc[n] = sXB[lc]; lcol[n] = labels[colBase + lc];
    }

    float pm2[2][4], nm2[2][4], cpm[2], cnm[2];
    #pragma unroll
    for (int m = 0; m < 2; ++m)
        #pragma unroll
        for (int j = 0; j < 4; ++j) { pm2[m][j] = 0.0f; nm2[m][j] = FLT_BIG; }
    #pragma unroll
    for (int n = 0; n < 2; ++n) { cpm[n] = 0.0f; cnm[n] = FLT_BIG; }

    #pragma unroll
    for (int m = 0; m < 2; ++m)
        #pragma unroll
        for (int n = 0; n < 2; ++n)
            #pragma unroll
            for (int j = 0; j < 4; ++j) {
                float d2 = fmaxf(xr[m][j] + xc[n] - 2.0f * acc[m][n][j], 0.0f);
                bool pos = (lrow[m][j] == lcol[n]);
                if (pos) {
                    pm2[m][j] = fmaxf(pm2[m][j], d2);
                    cpm[n]    = fmaxf(cpm[n],    d2);
                } else {
                    nm2[m][j] = fminf(nm2[m][j], d2);
                    cnm[n]    = fminf(cnm[n],    d2);
                }
            }

    #pragma unroll
    for (int m = 0; m < 2; ++m)
        #pragma unroll
        for (int j = 0; j < 4; ++j) {
            #pragma unroll
            for (int off = 1; off <= 8; off <<= 1) {
                pm2[m][j] = fmaxf(pm2[m][j], __shfl_xor(pm2[m][j], off));
                nm2[m][j] = fminf(nm2[m][j], __shfl_xor(nm2[m][j], off));
            }
        }
    #pragma unroll
    for (int n = 0; n < 2; ++n) {
        #pragma unroll
        for (int off = 16; off <= 32; off <<= 1) {
            cpm[n] = fmaxf(cpm[n], __shfl_xor(cpm[n], off));
            cnm[n] = fminf(cnm[n], __shfl_xor(cnm[n], off));
        }
    }

    if (l15 == 0) {
        #pragma unroll
        for (int m = 0; m < 2; ++m)
            #pragma unroll
            for (int j = 0; j < 4; ++j) {
                int r = m * 16 + (lane >> 4) * 4 + j;   // 0..31
                rp[wid][r] = pm2[m][j]; rn[wid][r] = nm2[m][j];
            }
    }
    if (lane < 16) {
        #pragma unroll
        for (int n = 0; n < 2; ++n) {
            int c = n * 16 + l15;                        // 0..31
            cp[wid][c] = cpm[n]; cn[wid][c] = cnm[n];
        }
    }
    __syncthreads();

    // partial stores (coherent, L2-bypassing): rows -> slot bj+1 of panel bi,
    // cols -> slot bi of panel bj. Each slot written exactly once per panel.
    if (tid < 64) {
        int r = tid, pair = (r >> 5) * 2, rr = r & 31;
        cstore(&pPart[(size_t)(bj + 1) * N + rowBase + r], fmaxf(rp[pair][rr], rp[pair + 1][rr]));
        cstore(&nPart[(size_t)(bj + 1) * N + rowBase + r], fminf(rn[pair][rr], rn[pair + 1][rr]));
    } else if (tid < 128) {
        int c = tid - 64, pair = c >> 5, cc = c & 31;
        cstore(&pPart[(size_t)bi * N + colBase + c], fmaxf(cp[pair][cc], cp[pair + 2][cc]));
        cstore(&nPart[(size_t)bi * N + colBase + c], fminf(cn[pair][cc], cn[pair + 2][cc]));
    }
    __syncthreads();   // drains vmcnt: all coherent stores complete before ticket

    // ---- per-panel tickets: the increment reaching NSLOT merges that panel ----
    if (tid == 0) {
        unsigned dA = (bi == bj) ? 2u : 1u;
        unsigned oldA = __hip_atomic_fetch_add(&panelCnt[bi], dA,
                            __ATOMIC_ACQ_REL, __HIP_MEMORY_SCOPE_AGENT);
        flags[0] = (oldA + dA == NSLOT);
        if (bi != bj) {
            unsigned oldB = __hip_atomic_fetch_add(&panelCnt[bj], 1u,
                                __ATOMIC_ACQ_REL, __HIP_MEMORY_SCOPE_AGENT);
            flags[1] = (oldB + 1u == NSLOT);
        } else {
            flags[1] = 0;
        }
    }
    __syncthreads();

    #pragma unroll
    for (int which = 0; which < 2; ++which) {
        if (!flags[which]) continue;
        const int q = which ? bj : bi;
        int r = tid & 63, w = tid >> 6;
        float mp = 0.0f, mn = FLT_BIG;
        for (int s = w; s < NSLOT; s += 4) {
            mp = fmaxf(mp, cload(&pPart[(size_t)s * N + q * 64 + r]));
            mn = fminf(mn, cload(&nPart[(size_t)s * N + q * 64 + r]));
        }
        mpL[w][r] = mp; mnL[w][r] = mn;
        __syncthreads();
        if (tid < 64) {
            float ap2 = fmaxf(fmaxf(mpL[0][tid], mpL[1][tid]),
                              fmaxf(mpL[2][tid], mpL[3][tid]));
            float an2 = fminf(fminf(mnL[0][tid], mnL[1][tid]),
                              fminf(mnL[2][tid], mnL[3][tid]));
            float ap = sqrtf(fmaxf(ap2, 1e-12f));
            float an = sqrtf(fmaxf(an2, 1e-12f));
            bool valid = (ap < 1.0e6f) && (an > 0.0f);
            float per = valid ? fmaxf(MARGIN + ap - an, 0.0f) : 0.0f;
            float cnt = valid ? 1.0f : 0.0f;
            #pragma unroll
            for (int off = 32; off >= 1; off >>= 1) {
                per += __shfl_xor(per, off);
                cnt += __shfl_xor(cnt, off);
            }
            if (tid == 0) {
                atomicAdd(&gacc[0], per);
                atomicAdd(&gacc[1], cnt);
                unsigned tk = __hip_atomic_fetch_add(ticket, 1u,
                                  __ATOMIC_ACQ_REL, __HIP_MEMORY_SCOPE_AGENT);
                if (tk == NPANEL - 1) {                // last panel merged
                    float St = cload(&gacc[0]);
                    float Ct = cload(&gacc[1]);
                    out[0] = (Ct > 0.0f) ? St / fmaxf(Ct, 1.0f) : 0.0f;
                }
            }
        }
        __syncthreads();                               // LDS reuse if 2nd merge
    }
}

extern "C" void kernel_launch(void* const* d_in, const int* in_sizes, int n_in,
                              void* d_out, int out_size, void* d_ws, size_t ws_size,
                              hipStream_t stream) {
    const float* feat = (const float*)d_in[0];
    const int* labels = (const int*)d_in[1];
    char* ws = (char*)d_ws;
    float*    gacc     = (float*)ws;                        // 8 B
    unsigned* ticket   = (unsigned*)(ws + 8);               // 4 B
    unsigned* panelCnt = (unsigned*)(ws + 16);              // 256 B
    float*    pPart    = (float*)(ws + 4096);               // 65*4096*4 B
    float*    nPart    = (float*)(ws + 4096 + (size_t)NSLOT * N * 4);
    float* out = (float*)d_out;

    hipMemsetAsync(ws, 0, 512, stream);   // zero gacc/ticket/panelCnt each call
    fused_kernel<<<NTILE, 256, 0, stream>>>(feat, labels, pPart, nPart,
                                            gacc, ticket, panelCnt, out);
}

// Round 11
// 96.087 us; speedup vs baseline: 2.4624x; 2.4624x over previous
//
#include <hip/hip_runtime.h>
#include <hip/hip_bf16.h>

#define N 4096
#define D 256
#define MARGIN 0.3f
#define NPANEL 64                       // 4096 / 64
#define NSLOT 65                        // slots per panel, each written exactly once
#define NTILE (NPANEL * (NPANEL + 1) / 2)   // 2080 triangular tiles
#define FLT_BIG 3.402823466e+38f

typedef __attribute__((ext_vector_type(8))) short short8;
typedef __attribute__((ext_vector_type(4))) float f32x4;

__device__ __forceinline__ ushort f2bf(float f) {
    unsigned u = __float_as_uint(f);
    return (ushort)((u + 0x7fffu + ((u >> 16) & 1u)) >> 16);   // RNE
}

// K1: fused fp32->bf16 staging + row norms + 64x64 triangular MFMA distance
// tile + masked row/col max/min partial stores. NO atomics, NO fences, NO
// agent-scope ops — cross-block visibility comes from the kernel boundary
// (rounds 9/10 measured: per-block coherence ops = full-L2 flush storms).
__global__ __launch_bounds__(256, 4) void tile_kernel(
        const float* __restrict__ feat, const int* __restrict__ labels,
        float* __restrict__ pPart, float* __restrict__ nPart) {
    __shared__ __attribute__((aligned(16))) short sA[64 * 64];   // 8 KB
    __shared__ __attribute__((aligned(16))) short sB[64 * 64];   // 8 KB
    __shared__ float rp[4][32], rn[4][32], cp[4][32], cn[4][32]; // 2 KB
    __shared__ float sXA[64], sXB[64];                           // 512 B

    const int tid  = threadIdx.x;
    const int lane = tid & 63;
    const int wid  = tid >> 6;

    // triangular decode: blockIdx.x -> (bi, bj) with bj >= bi
    int t = blockIdx.x, bi = 0, rem = NPANEL;
    while (t >= rem) { t -= rem; ++bi; --rem; }
    const int bj = bi + t;
    const int rowBase = bi * 64;
    const int colBase = bj * 64;

    // staging geometry: chunk c -> row c>>3, pre-swizzled k-chunk ((c^row)&7)*8
    const int row0 = tid >> 3;            // chunk c0 = tid       (rows 0..31)
    const int row1 = 32 + row0;           // chunk c1 = 256 + tid (rows 32..63)
    const int kc0  = ((tid ^ row0) & 7) * 8;
    const int kc1  = (((256 + tid) ^ row1) & 7) * 8;

    const int wr  = (wid >> 1) * 32;
    const int wc  = (wid & 1) * 32;
    const int l15 = lane & 15;
    const int kq  = (lane >> 4) * 8;
    const int swz = (lane & 7) << 3;      // ushort-index XOR swizzle

    float xA0 = 0.0f, xA1 = 0.0f, xB0 = 0.0f, xB1 = 0.0f;
    f32x4 acc[2][2] = {};

    for (int kt = 0; kt < D; kt += 64) {
        // ---- reg-stage fp32 -> bf16, accumulate squared norms ----
        {
            float4 a0 = *(const float4*)(feat + (size_t)(rowBase + row0) * D + kt + kc0);
            float4 a1 = *(const float4*)(feat + (size_t)(rowBase + row0) * D + kt + kc0 + 4);
            float4 a2 = *(const float4*)(feat + (size_t)(rowBase + row1) * D + kt + kc1);
            float4 a3 = *(const float4*)(feat + (size_t)(rowBase + row1) * D + kt + kc1 + 4);
            float4 b0 = *(const float4*)(feat + (size_t)(colBase + row0) * D + kt + kc0);
            float4 b1 = *(const float4*)(feat + (size_t)(colBase + row0) * D + kt + kc0 + 4);
            float4 b2 = *(const float4*)(feat + (size_t)(colBase + row1) * D + kt + kc1);
            float4 b3 = *(const float4*)(feat + (size_t)(colBase + row1) * D + kt + kc1 + 4);
            xA0 += a0.x*a0.x + a0.y*a0.y + a0.z*a0.z + a0.w*a0.w
                 + a1.x*a1.x + a1.y*a1.y + a1.z*a1.z + a1.w*a1.w;
            xA1 += a2.x*a2.x + a2.y*a2.y + a2.z*a2.z + a2.w*a2.w
                 + a3.x*a3.x + a3.y*a3.y + a3.z*a3.z + a3.w*a3.w;
            xB0 += b0.x*b0.x + b0.y*b0.y + b0.z*b0.z + b0.w*b0.w
                 + b1.x*b1.x + b1.y*b1.y + b1.z*b1.z + b1.w*b1.w;
            xB1 += b2.x*b2.x + b2.y*b2.y + b2.z*b2.z + b2.w*b2.w
                 + b3.x*b3.x + b3.y*b3.y + b3.z*b3.z + b3.w*b3.w;
            short8 sa0 = { (short)f2bf(a0.x), (short)f2bf(a0.y), (short)f2bf(a0.z), (short)f2bf(a0.w),
                           (short)f2bf(a1.x), (short)f2bf(a1.y), (short)f2bf(a1.z), (short)f2bf(a1.w) };
            short8 sa1 = { (short)f2bf(a2.x), (short)f2bf(a2.y), (short)f2bf(a2.z), (short)f2bf(a2.w),
                           (short)f2bf(a3.x), (short)f2bf(a3.y), (short)f2bf(a3.z), (short)f2bf(a3.w) };
            short8 sb0 = { (short)f2bf(b0.x), (short)f2bf(b0.y), (short)f2bf(b0.z), (short)f2bf(b0.w),
                           (short)f2bf(b1.x), (short)f2bf(b1.y), (short)f2bf(b1.z), (short)f2bf(b1.w) };
            short8 sb1 = { (short)f2bf(b2.x), (short)f2bf(b2.y), (short)f2bf(b2.z), (short)f2bf(b2.w),
                           (short)f2bf(b3.x), (short)f2bf(b3.y), (short)f2bf(b3.z), (short)f2bf(b3.w) };
            *(short8*)(sA + tid * 8)         = sa0;
            *(short8*)(sA + (256 + tid) * 8) = sa1;
            *(short8*)(sB + tid * 8)         = sb0;
            *(short8*)(sB + (256 + tid) * 8) = sb1;
        }
        __syncthreads();
        #pragma unroll
        for (int h = 0; h < 2; ++h) {
            short8 af[2], bfv[2];
            #pragma unroll
            for (int m = 0; m < 2; ++m) {
                int idx = ((wr + m * 16 + l15) << 6) + h * 32 + kq;
                af[m] = *(const short8*)(sA + (idx ^ swz));
            }
            #pragma unroll
            for (int n = 0; n < 2; ++n) {
                int idx = ((wc + n * 16 + l15) << 6) + h * 32 + kq;
                bfv[n] = *(const short8*)(sB + (idx ^ swz));
            }
            #pragma unroll
            for (int m = 0; m < 2; ++m)
                #pragma unroll
                for (int n = 0; n < 2; ++n)
                    acc[m][n] = __builtin_amdgcn_mfma_f32_16x16x32_bf16(
                        af[m], bfv[n], acc[m][n], 0, 0, 0);
        }
        __syncthreads();
    }

    // finalize row norms: sum the 8 chunk-threads of each row (lane bits 0..2)
    #pragma unroll
    for (int off = 1; off <= 4; off <<= 1) {
        xA0 += __shfl_xor(xA0, off); xA1 += __shfl_xor(xA1, off);
        xB0 += __shfl_xor(xB0, off); xB1 += __shfl_xor(xB1, off);
    }
    if ((lane & 7) == 0) {
        sXA[row0] = xA0; sXA[row1] = xA1;
        sXB[row0] = xB0; sXB[row1] = xB1;
    }
    __syncthreads();

    // ---- epilogue in d^2 domain ----
    float xr[2][4]; int lrow[2][4];
    #pragma unroll
    for (int m = 0; m < 2; ++m)
        #pragma unroll
        for (int j = 0; j < 4; ++j) {
            int lr = wr + m * 16 + (lane >> 4) * 4 + j;
            xr[m][j] = sXA[lr]; lrow[m][j] = labels[rowBase + lr];
        }
    float xc[2]; int lcol[2];
    #pragma unroll
    for (int n = 0; n < 2; ++n) {
        int lc = wc + n * 16 + l15;
        xc[n] = sXB[lc]; lcol[n] = labels[colBase + lc];
    }

    float pm2[2][4], nm2[2][4], cpm[2], cnm[2];
    #pragma unroll
    for (int m = 0; m < 2; ++m)
        #pragma unroll
        for (int j = 0; j < 4; ++j) { pm2[m][j] = 0.0f; nm2[m][j] = FLT_BIG; }
    #pragma unroll
    for (int n = 0; n < 2; ++n) { cpm[n] = 0.0f; cnm[n] = FLT_BIG; }

    #pragma unroll
    for (int m = 0; m < 2; ++m)
        #pragma unroll
        for (int n = 0; n < 2; ++n)
            #pragma unroll
            for (int j = 0; j < 4; ++j) {
                float d2 = fmaxf(xr[m][j] + xc[n] - 2.0f * acc[m][n][j], 0.0f);
                bool pos = (lrow[m][j] == lcol[n]);
                if (pos) {
                    pm2[m][j] = fmaxf(pm2[m][j], d2);
                    cpm[n]    = fmaxf(cpm[n],    d2);
                } else {
                    nm2[m][j] = fminf(nm2[m][j], d2);
                    cnm[n]    = fminf(cnm[n],    d2);
                }
            }

    #pragma unroll
    for (int m = 0; m < 2; ++m)
        #pragma unroll
        for (int j = 0; j < 4; ++j) {
            #pragma unroll
            for (int off = 1; off <= 8; off <<= 1) {
                pm2[m][j] = fmaxf(pm2[m][j], __shfl_xor(pm2[m][j], off));
                nm2[m][j] = fminf(nm2[m][j], __shfl_xor(nm2[m][j], off));
            }
        }
    #pragma unroll
    for (int n = 0; n < 2; ++n) {
        #pragma unroll
        for (int off = 16; off <= 32; off <<= 1) {
            cpm[n] = fmaxf(cpm[n], __shfl_xor(cpm[n], off));
            cnm[n] = fminf(cnm[n], __shfl_xor(cnm[n], off));
        }
    }

    if (l15 == 0) {
        #pragma unroll
        for (int m = 0; m < 2; ++m)
            #pragma unroll
            for (int j = 0; j < 4; ++j) {
                int r = m * 16 + (lane >> 4) * 4 + j;   // 0..31
                rp[wid][r] = pm2[m][j]; rn[wid][r] = nm2[m][j];
            }
    }
    if (lane < 16) {
        #pragma unroll
        for (int n = 0; n < 2; ++n) {
            int c = n * 16 + l15;                        // 0..31
            cp[wid][c] = cpm[n]; cn[wid][c] = cnm[n];
        }
    }
    __syncthreads();

    // plain partial stores: rows -> slot bj+1 of panel bi, cols -> slot bi of
    // panel bj. Each slot written exactly once per panel; K2 reads after the
    // kernel boundary (implicit device-level flush).
    if (tid < 64) {
        int r = tid, pair = (r >> 5) * 2, rr = r & 31;
        pPart[(size_t)(bj + 1) * N + rowBase + r] = fmaxf(rp[pair][rr], rp[pair + 1][rr]);
        nPart[(size_t)(bj + 1) * N + rowBase + r] = fminf(rn[pair][rr], rn[pair + 1][rr]);
    } else if (tid < 128) {
        int c = tid - 64, pair = c >> 5, cc = c & 31;
        pPart[(size_t)bi * N + colBase + c] = fmaxf(cp[pair][cc], cp[pair + 2][cc]);
        nPart[(size_t)bi * N + colBase + c] = fminf(cn[pair][cc], cn[pair + 2][cc]);
    }
}

// K2: merge 65 partial slots per row, margin-ranking loss, ticketed finalize.
// (Proven in rounds 5/6; only 16 blocks -> 16 fences total, negligible.)
__global__ __launch_bounds__(256) void merge_kernel(
        const float* __restrict__ pPart, const float* __restrict__ nPart,
        float* __restrict__ gacc, unsigned* __restrict__ ticket,
        float* __restrict__ out) {
    __shared__ float ssum[4], scnt[4];
    int i = blockIdx.x * 256 + threadIdx.x;
    float ap2 = 0.0f, an2 = FLT_BIG;
    #pragma unroll 5
    for (int s = 0; s < NSLOT; ++s) {
        ap2 = fmaxf(ap2, pPart[(size_t)s * N + i]);
        an2 = fminf(an2, nPart[(size_t)s * N + i]);
    }
    float ap = sqrtf(fmaxf(ap2, 1e-12f));
    float an = sqrtf(fmaxf(an2, 1e-12f));
    bool valid = (ap < 1.0e6f) && (an > 0.0f);
    float per = valid ? fmaxf(MARGIN + ap - an, 0.0f) : 0.0f;
    float cnt = valid ? 1.0f : 0.0f;
    #pragma unroll
    for (int off = 32; off >= 1; off >>= 1) {
        per += __shfl_xor(per, off);
        cnt += __shfl_xor(cnt, off);
    }
    int tid = threadIdx.x, wv = tid >> 6;
    if ((tid & 63) == 0) { ssum[wv] = per; scnt[wv] = cnt; }
    __syncthreads();
    if (tid == 0) {
        float S = ssum[0] + ssum[1] + ssum[2] + ssum[3];
        float C = scnt[0] + scnt[1] + scnt[2] + scnt[3];
        atomicAdd(&gacc[0], S);
        atomicAdd(&gacc[1], C);
        __threadfence();
        unsigned tk = atomicAdd(ticket, 1u);
        if (tk == gridDim.x - 1) {       // last block: all adds visible
            float St = atomicAdd(&gacc[0], 0.0f);
            float Ct = atomicAdd(&gacc[1], 0.0f);
            out[0] = (Ct > 0.0f) ? St / fmaxf(Ct, 1.0f) : 0.0f;
        }
    }
}

extern "C" void kernel_launch(void* const* d_in, const int* in_sizes, int n_in,
                              void* d_out, int out_size, void* d_ws, size_t ws_size,
                              hipStream_t stream) {
    const float* feat = (const float*)d_in[0];
    const int* labels = (const int*)d_in[1];
    char* ws = (char*)d_ws;
    float*    gacc   = (float*)ws;                          // 8 B
    unsigned* ticket = (unsigned*)(ws + 8);                 // 4 B
    float*    pPart  = (float*)(ws + 4096);                 // 65*4096*4 B
    float*    nPart  = (float*)(ws + 4096 + (size_t)NSLOT * N * 4);
    float* out = (float*)d_out;

    hipMemsetAsync(ws, 0, 64, stream);   // zero gacc/ticket each call
    tile_kernel<<<NTILE, 256, 0, stream>>>(feat, labels, pPart, nPart);
    merge_kernel<<<N / 256, 256, 0, stream>>>(pPart, nPart, gacc, ticket, out);
}